// Round 6
// baseline (417.648 us; speedup 1.0000x reference)
//
#include <hip/hip_runtime.h>
#include <math.h>

#define TTOK 16384
#define DD   4096
#define EE   64
#define TM   64
#define KC   128            // K per staged chunk (512 B per row-visit)
#define KSL  2
#define KW   (DD / KSL)     // 2048 K per block
#define NG   (KW / KC)      // 16 generations

typedef __attribute__((ext_vector_type(8))) short short8;
typedef __attribute__((ext_vector_type(4))) float f32x4;

static __device__ __forceinline__ unsigned short f2bf(float f) {
    unsigned u = __float_as_uint(f);
    u += 0x7FFFu + ((u >> 16) & 1u);          // RTNE
    return (unsigned short)(u >> 16);
}
static __device__ __forceinline__ float bf2f(unsigned short h) {
    return __uint_as_float(((unsigned)h) << 16);
}
static __device__ __forceinline__ void cvt8(float4 a, float4 b, short8& hi, short8& lo) {
    const float v[8] = {a.x, a.y, a.z, a.w, b.x, b.y, b.z, b.w};
#pragma unroll
    for (int j = 0; j < 8; ++j) {
        const unsigned short h = f2bf(v[j]);
        hi[j] = (short)h;
        lo[j] = (short)f2bf(v[j] - bf2f(h));
    }
}

__global__ void w_convert(const float* __restrict__ W,
                          unsigned short* __restrict__ whi,
                          unsigned short* __restrict__ wlo) {
    const int i = (blockIdx.x * blockDim.x + threadIdx.x) * 4;
    if (i >= EE * DD) return;
    const float4 v = *reinterpret_cast<const float4*>(W + i);
    ushort4 h, l;
    h.x = f2bf(v.x); l.x = f2bf(v.x - bf2f(h.x));
    h.y = f2bf(v.y); l.y = f2bf(v.y - bf2f(h.y));
    h.z = f2bf(v.z); l.z = f2bf(v.z - bf2f(h.z));
    h.w = f2bf(v.w); l.w = f2bf(v.w - bf2f(h.w));
    *reinterpret_cast<ushort4*>(whi + i) = h;
    *reinterpret_cast<ushort4*>(wlo + i) = l;
}

// grid 512: tile = bx & 255 (64 tokens), ksb = bx >> 8 (K-half).
// 512 threads = 8 waves; wave (g = wv&3, h = wv>>2) owns tokens 16g..+15, experts 32h..+31.
// Per gen: stage x fp32 (64x128, 512 B runs) + W hi/lo bf16; XOR-swizzled 16 B chunks.
__global__ __launch_bounds__(512, 4)
void gemm_part(const float* __restrict__ x,
               const unsigned short* __restrict__ whi,
               const unsigned short* __restrict__ wlo,
               float* __restrict__ part)
{
    __shared__ float          xs[TM * KC];    // 32 KB fp32 x
    __shared__ unsigned short whs[TM * KC];   // 16 KB W hi
    __shared__ unsigned short wls[TM * KC];   // 16 KB W lo

    const int tid  = threadIdx.x;
    const int wv   = tid >> 6;
    const int lane = tid & 63;
    const int m    = lane & 15;
    const int q    = lane >> 4;
    const int g    = wv & 3;        // token group
    const int h    = wv >> 2;       // expert half
    const int tile = blockIdx.x & 255;
    const int ksb  = blockIdx.x >> 8;
    const int t0   = tile * TM;
    const int k0   = ksb * KW;

    // staging: thread -> row sr (0..63), lane-in-row sl (0..7)
    const int sr = tid >> 3;
    const int sl = tid & 7;
    const int sk = sr & 7;                     // swizzle key for this row

    const float*          gx  = x   + (size_t)(t0 + sr) * DD + k0 + sl * 4;
    const unsigned short* gwh = whi + (size_t)sr * DD + k0 + sl * 16;
    const unsigned short* gwl = wlo + (size_t)sr * DD + k0 + sl * 16;

    // LDS store offsets
    int xo[4];
#pragma unroll
    for (int i = 0; i < 4; ++i) xo[i] = sr * KC + ((sl ^ sk) + 8 * i) * 4;
    const int wo0 = sr * KC + ((2 * sl    ) ^ sk) * 8;
    const int wo1 = sr * KC + ((2 * sl + 1) ^ sk) * 8;

    f32x4 acc[2];
    acc[0] = (f32x4){0.f, 0.f, 0.f, 0.f};
    acc[1] = (f32x4){0.f, 0.f, 0.f, 0.f};

    // prologue prefetch (gen 0)
    float4 px[4];
    short8 pwh[2], pwl[2];
#pragma unroll
    for (int i = 0; i < 4; ++i) px[i] = *reinterpret_cast<const float4*>(gx + 32 * i);
#pragma unroll
    for (int b = 0; b < 2; ++b) {
        pwh[b] = *reinterpret_cast<const short8*>(gwh + 8 * b);
        pwl[b] = *reinterpret_cast<const short8*>(gwl + 8 * b);
    }

    const int fk = m & 7;                      // frag swizzle key (rows 16g+m / 16et+m)
    const int ar = (16 * g + m) * KC;          // A row base (floats)

    for (int gen = 0; gen < NG; ++gen) {
        __syncthreads();   // previous gen's frag reads complete (+ prefetch drained)
#pragma unroll
        for (int i = 0; i < 4; ++i) *reinterpret_cast<float4*>(xs + xo[i]) = px[i];
        *reinterpret_cast<short8*>(whs + wo0) = pwh[0];
        *reinterpret_cast<short8*>(whs + wo1) = pwh[1];
        *reinterpret_cast<short8*>(wls + wo0) = pwl[0];
        *reinterpret_cast<short8*>(wls + wo1) = pwl[1];
        __syncthreads();   // staged data visible

        if (gen + 1 < NG) {
            const int off = (gen + 1) * KC;
#pragma unroll
            for (int i = 0; i < 4; ++i)
                px[i] = *reinterpret_cast<const float4*>(gx + off + 32 * i);
#pragma unroll
            for (int b = 0; b < 2; ++b) {
                pwh[b] = *reinterpret_cast<const short8*>(gwh + off + 8 * b);
                pwl[b] = *reinterpret_cast<const short8*>(gwl + off + 8 * b);
            }
        }

        // compute: 4 ks-steps of K=32
#pragma unroll
        for (int ks = 0; ks < 4; ++ks) {
            const int p0 = ks * 8 + ((2 * q    ) ^ fk);
            const int p1 = ks * 8 + ((2 * q + 1) ^ fk);
            const float4 f0 = *reinterpret_cast<const float4*>(xs + ar + p0 * 4);
            const float4 f1 = *reinterpret_cast<const float4*>(xs + ar + p1 * 4);
            short8 ah, al;
            cvt8(f0, f1, ah, al);
#pragma unroll
            for (int et = 0; et < 2; ++et) {
                const int br = ((32 * h + 16 * et) + m) * KC;
                const int pc = (ks * 4 + q) ^ fk;
                const short8 bh = *reinterpret_cast<const short8*>(whs + br + pc * 8);
                const short8 bl = *reinterpret_cast<const short8*>(wls + br + pc * 8);
                acc[et] = __builtin_amdgcn_mfma_f32_16x16x32_bf16(ah, bh, acc[et], 0, 0, 0);
                acc[et] = __builtin_amdgcn_mfma_f32_16x16x32_bf16(ah, bl, acc[et], 0, 0, 0);
                acc[et] = __builtin_amdgcn_mfma_f32_16x16x32_bf16(al, bh, acc[et], 0, 0, 0);
            }
        }
    }

    // partials: part[ksb][token][expert]; D layout col=m (expert), row=4q+i (token)
    float* pb = part + ((size_t)ksb * TTOK + t0 + 16 * g + 4 * q) * EE + 32 * h + m;
#pragma unroll
    for (int et = 0; et < 2; ++et)
#pragma unroll
        for (int i = 0; i < 4; ++i)
            pb[(size_t)i * EE + 16 * et] = acc[et][i];
}

__global__ __launch_bounds__(256, 4)
void gate_epi(const float* __restrict__ part, float* __restrict__ out)
{
    __shared__ float lg[TM * 68];
    __shared__ float s1a[TM], s2a[TM];
    __shared__ int   i1a[TM], i2a[TM];

    const int tid = threadIdx.x;
    const int t0  = blockIdx.x * TM;
    const int tt  = tid >> 2;           // token in tile
    const int e0  = (tid & 3) * 16;     // 16-expert span

    const float* pbase = part + (size_t)(t0 + tt) * EE + e0;
    float4 s[4];
#pragma unroll
    for (int j = 0; j < 4; ++j) s[j] = *reinterpret_cast<const float4*>(pbase + 4 * j);
#pragma unroll
    for (int k = 1; k < KSL; ++k) {
        const float* pk = pbase + (size_t)k * TTOK * EE;
#pragma unroll
        for (int j = 0; j < 4; ++j) {
            const float4 r = *reinterpret_cast<const float4*>(pk + 4 * j);
            s[j].x += r.x; s[j].y += r.y; s[j].z += r.z; s[j].w += r.w;
        }
    }
    float* gptr = out + (size_t)(t0 + tt) * EE + e0;
    float* lrow = lg + tt * 68 + e0;
#pragma unroll
    for (int j = 0; j < 4; ++j) {
        *reinterpret_cast<float4*>(gptr + 4 * j) = s[j];
        *reinterpret_cast<float4*>(lrow + 4 * j) = s[j];
    }
    __syncthreads();

    if (tid < TM) {
        const float* row = lg + tid * 68;
        float v1 = -INFINITY, v2 = -INFINITY;
        int   i1 = 0, i2 = 0;
        for (int e = 0; e < EE; ++e) {
            const float v = row[e];
            if (v > v1)      { v2 = v1; i2 = i1; v1 = v; i1 = e; }
            else if (v > v2) { v2 = v;  i2 = e; }
        }
        float sm = 0.f;
        for (int e = 0; e < EE; ++e) sm += expf(row[e] - v1);
        const float logz = v1 + logf(sm);
        out[(size_t)2 * TTOK * EE + t0 + tid] = logz * logz;
        const float e21 = expf(v2 - v1);
        const float rr  = 1.f / (1.f + e21);
        s1a[tid] = rr; s2a[tid] = e21 * rr; i1a[tid] = i1; i2a[tid] = i2;
    }
    __syncthreads();

    float* sc = out + (size_t)TTOK * EE + (size_t)(t0 + tt) * EE + e0;
    const int i1 = i1a[tt], i2 = i2a[tt];
    const float s1 = s1a[tt], s2 = s2a[tt];
#pragma unroll
    for (int j = 0; j < 4; ++j) {
        float vv[4];
#pragma unroll
        for (int c = 0; c < 4; ++c) {
            const int e = e0 + 4 * j + c;
            vv[c] = (e == i1) ? s1 : ((e == i2) ? s2 : 0.f);
        }
        *reinterpret_cast<float4*>(sc + 4 * j) = make_float4(vv[0], vv[1], vv[2], vv[3]);
    }
}

extern "C" void kernel_launch(void* const* d_in, const int* in_sizes, int n_in,
                              void* d_out, int out_size, void* d_ws, size_t ws_size,
                              hipStream_t stream) {
    const float* x = (const float*)d_in[0];
    const float* W = (const float*)d_in[1];
    float* out = (float*)d_out;
    unsigned short* whi = (unsigned short*)d_ws;
    unsigned short* wlo = whi + (size_t)EE * DD;
    float* part = (float*)(wlo + (size_t)EE * DD);   // KSL * TTOK * EE floats = 8 MB

    w_convert<<<dim3(EE * DD / 4 / 256), dim3(256), 0, stream>>>(W, whi, wlo);
    gemm_part<<<dim3(256 * KSL), dim3(512), 0, stream>>>(x, whi, wlo, part);
    gate_epi<<<dim3(TTOK / TM), dim3(256), 0, stream>>>(part, out);
}